// Round 11
// baseline (4164.800 us; speedup 1.0000x reference)
//
#include <hip/hip_runtime.h>
#include <math.h>

#define Tt 4096
#define NB 16

#define CLN2PI 1.8378770664093453f   // ln(2*pi)
#define CLN2   0.6931471805599453f   // ln(2)

// ws layout (float offsets)
#define OFF_W    0         // 131072  W = L^-1 per state (row-major, upper zeros)
#define OFF_D    131072    // 2048    d = W*mu
#define OFF_CST  133120    // 32      F*ln2pi + logdet  (nats)
#define OFF_EV   133152    // 16      evidence per batch (fp32 nats)
#define OFF_LB   133184    // 2097152 logB nats [b][t][s]
#define OFF_BET  2230336   // 2097152 beta  nats [b][t][s]
// total 4327488 floats = 17.3 MB

__device__ __forceinline__ float rdlane(float x, int l) {
  return __int_as_float(__builtin_amdgcn_readlane(__float_as_int(x), l));
}

// Per-lane cross-half exchange via v_permlane32_swap (VALU, ~10cy).
// With old=src=v: lo = v[lane&31], hi = v[32|(lane&31)] in ALL lanes.
// R4 lesson: inline-asm w/ two identical tied operands coalesces -> garbage;
// the intrinsic models both results -> safe. R5 lesson: rdlane(x, fixed_lane)
// only valid for wave-uniform x.
typedef unsigned int u32x2 __attribute__((ext_vector_type(2)));
__device__ __forceinline__ void xhalf(float v, float& lo, float& hi) {
  u32x2 r = __builtin_amdgcn_permlane32_swap(__float_as_uint(v), __float_as_uint(v),
                                             false, false);
  lo = __uint_as_float(r.x);
  hi = __uint_as_float(r.y);
}

// ---------------- K2: per-state Cholesky, W = L^-1, d = W*mu, cst ----------------
__global__ __launch_bounds__(64) void k_chol(const float* __restrict__ covs,
                                             const float* __restrict__ means,
                                             float* __restrict__ ws) {
  __shared__ float Am[64][65];
  __shared__ float Wl[64][65];
  int s = blockIdx.x, j = threadIdx.x;
  for (int r = 0; r < 64; ++r) {
    Am[r][j] = covs[((size_t)s * 64 + r) * 64 + j];
    Wl[r][j] = 0.f;
  }
  __syncthreads();
  for (int k = 0; k < 64; ++k) {
    float diag = sqrtf(Am[k][k]);
    float col = (j > k) ? Am[j][k] / diag : 0.f;
    __syncthreads();
    if (j == k) Am[k][k] = diag;
    if (j > k)  Am[j][k] = col;
    __syncthreads();
    if (j > k) {
      for (int g = k + 1; g <= j; ++g) Am[j][g] -= col * Am[g][k];
    }
    __syncthreads();
  }
  {
    int c = j;
    Wl[c][c] = 1.0f / Am[c][c];
    for (int f = c + 1; f < 64; ++f) {
      float ssum = 0.f;
      for (int g = c; g < f; ++g) ssum += Am[f][g] * Wl[g][c];
      Wl[f][c] = -ssum / Am[f][f];
    }
  }
  __syncthreads();
  for (int r = 0; r < 64; ++r)
    ws[OFF_W + ((size_t)s * 64 + r) * 64 + j] = Wl[r][j];
  {
    float acc = 0.f;
    for (int g = 0; g < 64; ++g) acc += Wl[j][g] * means[s * 64 + g];
    ws[OFF_D + s * 64 + j] = acc;
  }
  if (j == 0) {
    float logdet = 0.f;
    for (int k = 0; k < 64; ++k) logdet += __logf(Am[k][k]);
    logdet *= 2.0f;
    ws[OFF_CST + s] = 64.0f * CLN2PI + logdet;
  }
}

// ---------------- K3: emission logB (nats) ----------------
// R11: same fma ORDER as R0-R10 (bit-identical logB), but the f-loop is no
// longer fully unrolled. The unrolled body was ~26KB of straight-line code
// per state — I-cache thrash is the leading theory for k_emis running ~7x
// over its 70us compute floor (R10 showed load-vectorization was already
// done by the compiler -> neutral). Dynamic chunk bound keeps the body ~100B.
__global__ __launch_bounds__(64) void k_emis(const float* __restrict__ x,
                                             const float* __restrict__ wsr,
                                             float* __restrict__ lb) {
  const float* W = wsr + OFF_W;
  const float* D = wsr + OFF_D;
  const float* C = wsr + OFF_CST;
  int bx = blockIdx.x;
  int sgrp = bx & 3;
  int pt = (bx >> 2) * 64 + threadIdx.x;
  const float* xr = x + (size_t)pt * 64;
  float xv[64];
#pragma unroll
  for (int c = 0; c < 16; ++c) {
    float4 q = ((const float4*)xr)[c];
    xv[4 * c + 0] = q.x; xv[4 * c + 1] = q.y;
    xv[4 * c + 2] = q.z; xv[4 * c + 3] = q.w;
  }
#pragma unroll 1
  for (int si = 0; si < 8; ++si) {
    int s = sgrp * 8 + si;
    const float* Ws = W + (size_t)s * 4096;
    const float* Ds = D + s * 64;
    float maha = 0.f;
#pragma unroll 1
    for (int f = 0; f < 64; ++f) {
      float z = -Ds[f];
      int nch = (f >> 4) + 1;
#pragma unroll 1
      for (int ch = 0; ch < nch; ++ch) {
        const float4* Wq = (const float4*)(Ws + f * 64 + ch * 16);
        float4 w0 = Wq[0], w1 = Wq[1], w2 = Wq[2], w3 = Wq[3];
        const float* xc = xv + ch * 16;
        z = fmaf(w0.x, xc[ 0], z);
        z = fmaf(w0.y, xc[ 1], z);
        z = fmaf(w0.z, xc[ 2], z);
        z = fmaf(w0.w, xc[ 3], z);
        z = fmaf(w1.x, xc[ 4], z);
        z = fmaf(w1.y, xc[ 5], z);
        z = fmaf(w1.z, xc[ 6], z);
        z = fmaf(w1.w, xc[ 7], z);
        z = fmaf(w2.x, xc[ 8], z);
        z = fmaf(w2.y, xc[ 9], z);
        z = fmaf(w2.z, xc[10], z);
        z = fmaf(w2.w, xc[11], z);
        z = fmaf(w3.x, xc[12], z);
        z = fmaf(w3.y, xc[13], z);
        z = fmaf(w3.z, xc[14], z);
        z = fmaf(w3.w, xc[15], z);
      }
      maha = fmaf(z, z, maha);
    }
    lb[(size_t)pt * 32 + s] = -0.5f * (maha + C[s]);
  }
}

// np-pairwise-order sum of 32 (evidence only)
__device__ __forceinline__ float npsum32(const float* z) {
  float r[8];
#pragma unroll
  for (int k = 0; k < 8; ++k)
    r[k] = ((z[k] + z[k + 8]) + z[k + 16]) + z[k + 24];
  return ((r[0] + r[1]) + (r[2] + r[3])) + ((r[4] + r[5]) + (r[6] + r[7]));
}
// exact max of 32 (order-independent, commutative -> any tree ok)
__device__ __forceinline__ float max32(const float* z) {
  float t16[16];
#pragma unroll
  for (int k = 0; k < 16; ++k) t16[k] = fmaxf(z[k], z[k + 16]);
  float t8[8];
#pragma unroll
  for (int k = 0; k < 8; ++k) t8[k] = fmaxf(t16[k], t16[k + 8]);
  float t4[4];
#pragma unroll
  for (int k = 0; k < 4; ++k) t4[k] = fmaxf(t8[k], t8[k + 4]);
  float t2a = fmaxf(t4[0], t4[2]), t2b = fmaxf(t4[1], t4[3]);
  return fmaxf(t2a, t2b);
}
// exact max of 16 (commutative -> any tree yields THE max, bit-exact)
__device__ __forceinline__ float max16(const float* z) {
  float t8[8];
#pragma unroll
  for (int k = 0; k < 8; ++k) t8[k] = fmaxf(z[k], z[k + 8]);
  float t4[4];
#pragma unroll
  for (int k = 0; k < 4; ++k) t4[k] = fmaxf(t8[k], t8[k + 4]);
  return fmaxf(fmaxf(t4[0], t4[2]), fmaxf(t4[1], t4[3]));
}
// tree sum of 16 (reassociated small-value sum: R6-proven safe class)
__device__ __forceinline__ float sum16(const float* e) {
  float t8[8];
#pragma unroll
  for (int k = 0; k < 8; ++k) t8[k] = e[k] + e[k + 8];
  float t4[4];
#pragma unroll
  for (int k = 0; k < 4; ++k) t4[k] = t8[k] + t8[k + 4];
  return (t4[0] + t4[2]) + (t4[1] + t4[3]);
}

// ---------------- K4: forward/backward, fp32 nats ----------------
// R10 analysis: step time = (dependent VALU hops) x ~48cy at 1 wave/SIMD
// (R0:24 hops/1164cy, R6:21/1010, R3:17+4 LDS/1165, R8:+LDS/1375). So cut
// HOPS. R11 = deferred-max: exp uses predicted shift mhat = a_j(prev)+24
// (0 hops, per-lane), the NP-EXACT max tree of z runs OFF the critical path,
// and the result is fixed up after the sum:
//   corr   = mhat - m              (Sterbenz-exact: both ~|3.6e5|, within 2x)
//   logS'' = fmaf(log2(S'), ln2, corr)   ~= np logS +- 1e-5 abs
//   a      = (logS'' + m) + bcur   (np-ordered big adds, m = np's exact max)
// Error class: exp/log value perturbations ~1e-5 abs in logS — R6/R8-proven
// safe (flip prob ~3e-4/step -> ~0.03 extra drift). R9's failure axis (the
// big-magnitude add operands) is untouched: z, m, bcur are bit-identical.
// Range guard: z - mhat <= spread(alpha)+12-24; data spread ~40-60 << 88.
// Path: 21 -> 15 hops (gather, z, sub, mul, exp, 4-sum, permlane, add,
// log2, fmaf-fixup, +m, +bcur).
__global__ __launch_bounds__(64, 1) __attribute__((amdgpu_waves_per_eu(1)))
void k_fb(const float* __restrict__ logA,
          const float* __restrict__ logpi,
          float* __restrict__ ws,
          float* __restrict__ out) {
  const float* lbg = ws + OFF_LB;
  float* bet = ws + OFF_BET;
  float* ev  = ws + OFF_EV;
  int chain = blockIdx.x;
  int b   = chain & 15;
  int dir = chain >> 4;
  int lane = threadIdx.x;
  int j = lane & 31;
  int h = lane >> 5;
  int i0 = h << 4;                       // first reduction index this half owns
  const float* lb = lbg + (size_t)b * Tt * 32;

  if (dir == 0) {
    float acol[16];                      // A[i0+k][j]
#pragma unroll
    for (int k = 0; k < 16; ++k) {
      acol[k] = logA[(i0 + k) * 32 + j];
      asm volatile("" : "+v"(acol[k]));
    }
    float* ao = out + (size_t)b * Tt * 32;
    float a = logpi[j] + lb[j];          // alpha[0], identical in both halves
    ao[j] = a;
    float mhat = a + 24.0f;              // deferred-max predictor (per-j)
    float bA = lb[32 + j];
    float bB = lb[64 + j];
    float bC = lb[96 + j];
#pragma unroll 1
    for (int t = 1; t < Tt; ++t) {
      float bcur = bA; bA = bB; bB = bC;
      if (t + 3 < Tt) bC = lb[(size_t)(t + 3) * 32 + j];
      float sa[32];                      // uniform (SGPR) gather of a-vector
#pragma unroll
      for (int i = 0; i < 32; ++i) sa[i] = rdlane(a, i);
      float z[16];
      if (h == 0) {
#pragma unroll
        for (int k = 0; k < 16; ++k) z[k] = sa[k] + acol[k];      // np-exact z
      } else {
#pragma unroll
        for (int k = 0; k < 16; ++k) z[k] = sa[16 + k] + acol[k];
      }
      float e[16];
#pragma unroll
      for (int k = 0; k < 16; ++k) e[k] = __expf(z[k] - mhat);   // exact sub
      // np-exact max tree — off the critical path (needs z only)
      float mh = max16(z);
      float mlo, mhi;
      xhalf(mh, mlo, mhi);
      float m = fmaxf(mlo, mhi);         // np's exact max, same bits all lanes
      float sh = sum16(e);
      float slo, shi;
      xhalf(sh, slo, shi);
      float S = slo + shi;               // S' = S_np * e^{m-mhat} * (1+~1e-7)
      float corr = mhat - m;             // exact
      float lgS = fmaf(__log2f(S), CLN2, corr);   // ~= np logS (+-1e-5)
      a = (lgS + m) + bcur;              // np-ordered big adds
      ao[(size_t)t * 32 + j] = a;        // halves write same value -> safe
      mhat = a + 24.0f;
    }
    // evidence = logsumexp(alpha[T-1]) — np-exact, identical to baseline
    float z[32];
#pragma unroll
    for (int i = 0; i < 32; ++i) z[i] = rdlane(a, i);
    float m = max32(z);
#pragma unroll
    for (int i = 0; i < 32; ++i) z[i] = __expf(z[i] - m);
    float S = npsum32(z);
    if (lane == 0) ev[b] = __logf(S) + m;
  } else {
    float arow[16];                      // A[j][i0+k]
#pragma unroll
    for (int k = 0; k < 16; ++k) {
      arow[k] = logA[j * 32 + i0 + k];
      asm volatile("" : "+v"(arow[k]));
    }
    float* bo = bet + (size_t)b * Tt * 32;
    bo[(size_t)(Tt - 1) * 32 + j] = 0.f;
    float y = lb[(size_t)(Tt - 1) * 32 + j] + 0.f;   // (logB[T-1] + beta[T-1])
    float mhat = y + 24.0f;
    float bA = lb[(size_t)(Tt - 2) * 32 + j];
    float bB = lb[(size_t)(Tt - 3) * 32 + j];
    float bC = lb[(size_t)(Tt - 4) * 32 + j];
#pragma unroll 1
    for (int t = Tt - 2; t >= 0; --t) {
      float bcur = bA; bA = bB; bB = bC;
      if (t >= 3) bC = lb[(size_t)(t - 3) * 32 + j];
      float sy[32];                      // uniform (SGPR) gather of y-vector
#pragma unroll
      for (int i = 0; i < 32; ++i) sy[i] = rdlane(y, i);
      float z[16];
      if (h == 0) {
#pragma unroll
        for (int k = 0; k < 16; ++k) z[k] = arow[k] + sy[k];      // np-exact z
      } else {
#pragma unroll
        for (int k = 0; k < 16; ++k) z[k] = arow[k] + sy[16 + k];
      }
      float e[16];
#pragma unroll
      for (int k = 0; k < 16; ++k) e[k] = __expf(z[k] - mhat);
      float mh = max16(z);
      float mlo, mhi;
      xhalf(mh, mlo, mhi);
      float m = fmaxf(mlo, mhi);         // np's exact max
      float sh = sum16(e);
      float slo, shi;
      xhalf(sh, slo, shi);
      float S = slo + shi;
      float corr = mhat - m;
      float lgS = fmaf(__log2f(S), CLN2, corr);
      float bv = lgS + m;                // beta[t][j], same bits both halves
      bo[(size_t)t * 32 + j] = bv;
      y = bcur + bv;                     // np-ordered
      mhat = y + 24.0f;
    }
  }
}

// ---------------- K5: gamma = (alpha + beta) - evidence, fp32 ----------------
__global__ void k_gamma(const float* __restrict__ ws, float* __restrict__ out) {
  size_t idx = (size_t)blockIdx.x * blockDim.x + threadIdx.x;
  if (idx >= (size_t)NB * Tt * 32) return;
  int b = (int)(idx >> 17);            // T*S = 131072
  float a  = out[idx];
  float bb = ws[OFF_BET + idx];
  float e  = ws[OFF_EV + b];
  out[idx] = (a + bb) - e;
}

extern "C" void kernel_launch(void* const* d_in, const int* in_sizes, int n_in,
                              void* d_out, int out_size, void* d_ws, size_t ws_size,
                              hipStream_t stream) {
  const float* x     = (const float*)d_in[0];
  const float* means = (const float*)d_in[1];
  const float* covs  = (const float*)d_in[2];
  const float* logA  = (const float*)d_in[3];
  const float* logpi = (const float*)d_in[4];
  float* ws  = (float*)d_ws;
  float* out = (float*)d_out;

  k_chol<<<dim3(32), dim3(64), 0, stream>>>(covs, means, ws);
  k_emis<<<dim3(4096), dim3(64), 0, stream>>>(x, ws, ws + OFF_LB);
  k_fb<<<dim3(32), dim3(64), 0, stream>>>(logA, logpi, ws, out);
  k_gamma<<<dim3(8192), dim3(256), 0, stream>>>(ws, out);
}

// Round 12
// 2163.448 us; speedup vs baseline: 1.9251x; 1.9251x over previous
//
#include <hip/hip_runtime.h>
#include <math.h>

#define Tt 4096
#define NB 16

#define CLN2PI 1.8378770664093453f   // ln(2*pi)

// ws layout (float offsets)
#define OFF_W    0         // 131072  W = L^-1 per state (row-major, upper zeros)
#define OFF_D    131072    // 2048    d = W*mu
#define OFF_CST  133120    // 32      F*ln2pi + logdet  (nats)
#define OFF_EV   133152    // 16      evidence per batch (fp32 nats)
#define OFF_LB   133184    // 2097152 logB nats [b][t][s]
#define OFF_BET  2230336   // 2097152 beta  nats [b][t][s]
// total 4327488 floats = 17.3 MB

__device__ __forceinline__ float rdlane(float x, int l) {
  return __int_as_float(__builtin_amdgcn_readlane(__float_as_int(x), l));
}

// Per-lane cross-half exchange via v_permlane32_swap (VALU, ~10cy).
// With old=src=v: lo = v[lane&31], hi = v[32|(lane&31)] in ALL lanes.
// R4 lesson: inline-asm w/ two identical tied operands coalesces -> garbage;
// the intrinsic models both results -> safe. R5 lesson: rdlane(x, fixed_lane)
// only valid for wave-uniform x.
typedef unsigned int u32x2 __attribute__((ext_vector_type(2)));
__device__ __forceinline__ void xhalf(float v, float& lo, float& hi) {
  u32x2 r = __builtin_amdgcn_permlane32_swap(__float_as_uint(v), __float_as_uint(v),
                                             false, false);
  lo = __uint_as_float(r.x);
  hi = __uint_as_float(r.y);
}

// ---------------- K2: per-state Cholesky, W = L^-1, d = W*mu, cst ----------------
__global__ __launch_bounds__(64) void k_chol(const float* __restrict__ covs,
                                             const float* __restrict__ means,
                                             float* __restrict__ ws) {
  __shared__ float Am[64][65];
  __shared__ float Wl[64][65];
  int s = blockIdx.x, j = threadIdx.x;
  for (int r = 0; r < 64; ++r) {
    Am[r][j] = covs[((size_t)s * 64 + r) * 64 + j];
    Wl[r][j] = 0.f;
  }
  __syncthreads();
  for (int k = 0; k < 64; ++k) {
    float diag = sqrtf(Am[k][k]);
    float col = (j > k) ? Am[j][k] / diag : 0.f;
    __syncthreads();
    if (j == k) Am[k][k] = diag;
    if (j > k)  Am[j][k] = col;
    __syncthreads();
    if (j > k) {
      for (int g = k + 1; g <= j; ++g) Am[j][g] -= col * Am[g][k];
    }
    __syncthreads();
  }
  {
    int c = j;
    Wl[c][c] = 1.0f / Am[c][c];
    for (int f = c + 1; f < 64; ++f) {
      float ssum = 0.f;
      for (int g = c; g < f; ++g) ssum += Am[f][g] * Wl[g][c];
      Wl[f][c] = -ssum / Am[f][f];
    }
  }
  __syncthreads();
  for (int r = 0; r < 64; ++r)
    ws[OFF_W + ((size_t)s * 64 + r) * 64 + j] = Wl[r][j];
  {
    float acc = 0.f;
    for (int g = 0; g < 64; ++g) acc += Wl[j][g] * means[s * 64 + g];
    ws[OFF_D + s * 64 + j] = acc;
  }
  if (j == 0) {
    float logdet = 0.f;
    for (int k = 0; k < 64; ++k) logdet += __logf(Am[k][k]);
    logdet *= 2.0f;
    ws[OFF_CST + s] = 64.0f * CLN2PI + logdet;
  }
}

// 16-wide dot with STATIC xv indexing. xc MUST be xv + compile-time-constant
// offset (R11 lesson / rule #20: xv + runtime*16 -> dynamic index -> xv[64]
// demoted to scratch -> k_emis 470 -> 2396us, FETCH 3.95GB. Never again.)
__device__ __forceinline__ float dot16w(const float* __restrict__ w,
                                        const float* xc, float z) {
  float4 w0 = ((const float4*)w)[0];
  float4 w1 = ((const float4*)w)[1];
  float4 w2 = ((const float4*)w)[2];
  float4 w3 = ((const float4*)w)[3];
  z = fmaf(w0.x, xc[ 0], z);
  z = fmaf(w0.y, xc[ 1], z);
  z = fmaf(w0.z, xc[ 2], z);
  z = fmaf(w0.w, xc[ 3], z);
  z = fmaf(w1.x, xc[ 4], z);
  z = fmaf(w1.y, xc[ 5], z);
  z = fmaf(w1.z, xc[ 6], z);
  z = fmaf(w1.w, xc[ 7], z);
  z = fmaf(w2.x, xc[ 8], z);
  z = fmaf(w2.y, xc[ 9], z);
  z = fmaf(w2.z, xc[10], z);
  z = fmaf(w2.w, xc[11], z);
  z = fmaf(w3.x, xc[12], z);
  z = fmaf(w3.y, xc[13], z);
  z = fmaf(w3.z, xc[14], z);
  z = fmaf(w3.w, xc[15], z);
  return z;
}

// ---------------- K3: emission logB (nats) ----------------
// R12: same fma ORDER over (g, f, s) as R0-R10 -> BIT-IDENTICAL logB.
// Change: the f-loop is rolled into 4 range-loops (1/2/3/4 chunk calls),
// shrinking the body from ~30KB straight-line (full unroll, streamed through
// 32KB L1I every si iteration) to ~3KB. xv indices stay compile-time static
// via constant-offset subarray pointers (xv, xv+16, xv+32, xv+48).
__global__ __launch_bounds__(64) void k_emis(const float* __restrict__ x,
                                             const float* __restrict__ wsr,
                                             float* __restrict__ lb) {
  const float* W = wsr + OFF_W;
  const float* D = wsr + OFF_D;
  const float* C = wsr + OFF_CST;
  int bx = blockIdx.x;
  int sgrp = bx & 3;
  int pt = (bx >> 2) * 64 + threadIdx.x;
  const float* xr = x + (size_t)pt * 64;
  float xv[64];
#pragma unroll
  for (int c = 0; c < 16; ++c) {
    float4 q = ((const float4*)xr)[c];
    xv[4 * c + 0] = q.x; xv[4 * c + 1] = q.y;
    xv[4 * c + 2] = q.z; xv[4 * c + 3] = q.w;
  }
#pragma unroll 1
  for (int si = 0; si < 8; ++si) {
    int s = sgrp * 8 + si;
    const float* Ws = W + (size_t)s * 4096;
    const float* Ds = D + s * 64;
    float maha = 0.f;
#pragma unroll 1
    for (int f = 0; f < 16; ++f) {
      float z = -Ds[f];
      const float* Wf = Ws + f * 64;
      z = dot16w(Wf, xv, z);
      maha = fmaf(z, z, maha);
    }
#pragma unroll 1
    for (int f = 16; f < 32; ++f) {
      float z = -Ds[f];
      const float* Wf = Ws + f * 64;
      z = dot16w(Wf,      xv,      z);
      z = dot16w(Wf + 16, xv + 16, z);
      maha = fmaf(z, z, maha);
    }
#pragma unroll 1
    for (int f = 32; f < 48; ++f) {
      float z = -Ds[f];
      const float* Wf = Ws + f * 64;
      z = dot16w(Wf,      xv,      z);
      z = dot16w(Wf + 16, xv + 16, z);
      z = dot16w(Wf + 32, xv + 32, z);
      maha = fmaf(z, z, maha);
    }
#pragma unroll 1
    for (int f = 48; f < 64; ++f) {
      float z = -Ds[f];
      const float* Wf = Ws + f * 64;
      z = dot16w(Wf,      xv,      z);
      z = dot16w(Wf + 16, xv + 16, z);
      z = dot16w(Wf + 32, xv + 32, z);
      z = dot16w(Wf + 48, xv + 48, z);
      maha = fmaf(z, z, maha);
    }
    lb[(size_t)pt * 32 + s] = -0.5f * (maha + C[s]);
  }
}

// np-pairwise-order sum of 32 (evidence only)
__device__ __forceinline__ float npsum32(const float* z) {
  float r[8];
#pragma unroll
  for (int k = 0; k < 8; ++k)
    r[k] = ((z[k] + z[k + 8]) + z[k + 16]) + z[k + 24];
  return ((r[0] + r[1]) + (r[2] + r[3])) + ((r[4] + r[5]) + (r[6] + r[7]));
}
// exact max of 32 (order-independent, commutative -> any tree ok)
__device__ __forceinline__ float max32(const float* z) {
  float t16[16];
#pragma unroll
  for (int k = 0; k < 16; ++k) t16[k] = fmaxf(z[k], z[k + 16]);
  float t8[8];
#pragma unroll
  for (int k = 0; k < 8; ++k) t8[k] = fmaxf(t16[k], t16[k + 8]);
  float t4[4];
#pragma unroll
  for (int k = 0; k < 4; ++k) t4[k] = fmaxf(t8[k], t8[k + 4]);
  float t2a = fmaxf(t4[0], t4[2]), t2b = fmaxf(t4[1], t4[3]);
  return fmaxf(t2a, t2b);
}
// exact max of 16 (commutative -> any tree yields THE max, bit-exact)
__device__ __forceinline__ float max16(const float* z) {
  float t8[8];
#pragma unroll
  for (int k = 0; k < 8; ++k) t8[k] = fmaxf(z[k], z[k + 8]);
  float t4[4];
#pragma unroll
  for (int k = 0; k < 4; ++k) t4[k] = fmaxf(t8[k], t8[k + 4]);
  return fmaxf(fmaxf(t4[0], t4[2]), fmaxf(t4[1], t4[3]));
}
// tree sum of 16 (reassociated small-value sum: R6-proven safe class.
// R9 closed the safe set: ONLY post-exp small-value reassociation and lane
// redistribution are allowed; all big-magnitude roundings (z-adds, logS+m,
// +bcur) and the exp inputs must replicate np bit-exactly.)
__device__ __forceinline__ float sum16(const float* e) {
  float t8[8];
#pragma unroll
  for (int k = 0; k < 8; ++k) t8[k] = e[k] + e[k + 8];
  float t4[4];
#pragma unroll
  for (int k = 0; k < 4; ++k) t4[k] = t8[k] + t8[k + 4];
  return (t4[0] + t4[2]) + (t4[1] + t4[3]);
}

// ---------------- K4: forward/backward, fp32 nats (R6, best verified) ----------------
// 1 wave per (batch, dir). Half-split: lane (h=lane>>5, j=lane&31) owns
// reduction indices i in [16h,16h+16) for state j -> 16 exps/step not 32.
// Structure locked by R7-R11: one wave/chain; step pinned at ~1010 cyc
// regardless of dep-hop count (R11 deferred-max: 15 hops, same time) — the
// step is issue/fixed-cost-bound, not hop-latency-bound. Don't touch.
__global__ __launch_bounds__(64, 1) __attribute__((amdgpu_waves_per_eu(1)))
void k_fb(const float* __restrict__ logA,
          const float* __restrict__ logpi,
          float* __restrict__ ws,
          float* __restrict__ out) {
  const float* lbg = ws + OFF_LB;
  float* bet = ws + OFF_BET;
  float* ev  = ws + OFF_EV;
  int chain = blockIdx.x;
  int b   = chain & 15;
  int dir = chain >> 4;
  int lane = threadIdx.x;
  int j = lane & 31;
  int h = lane >> 5;
  int i0 = h << 4;                       // first reduction index this half owns
  const float* lb = lbg + (size_t)b * Tt * 32;

  if (dir == 0) {
    float acol[16];                      // A[i0+k][j]
#pragma unroll
    for (int k = 0; k < 16; ++k) {
      acol[k] = logA[(i0 + k) * 32 + j];
      asm volatile("" : "+v"(acol[k]));
    }
    float* ao = out + (size_t)b * Tt * 32;
    float a = logpi[j] + lb[j];          // alpha[0], identical in both halves
    ao[j] = a;
    float bA = lb[32 + j];
    float bB = lb[64 + j];
    float bC = lb[96 + j];
#pragma unroll 1
    for (int t = 1; t < Tt; ++t) {
      float bcur = bA; bA = bB; bB = bC;
      if (t + 3 < Tt) bC = lb[(size_t)(t + 3) * 32 + j];
      float sa[32];                      // uniform (SGPR) gather of a-vector
#pragma unroll
      for (int i = 0; i < 32; ++i) sa[i] = rdlane(a, i);
      float z[16];
      if (h == 0) {
#pragma unroll
        for (int k = 0; k < 16; ++k) z[k] = sa[k] + acol[k];      // a_i + A[i][j]
      } else {
#pragma unroll
        for (int k = 0; k < 16; ++k) z[k] = sa[16 + k] + acol[k];
      }
      float mh = max16(z);               // per-(half,j) exact max
      float mlo, mhi;
      xhalf(mh, mlo, mhi);               // partner exchange (same j)
      float m = fmaxf(mlo, mhi);         // full max_i, same bits all lanes
      float e[16];
#pragma unroll
      for (int k = 0; k < 16; ++k) e[k] = __expf(z[k] - m);  // z-m exact
      float sh = sum16(e);               // per-(half,j) tree sum
      float slo, shi;
      xhalf(sh, slo, shi);
      float S = slo + shi;               // full sum, same bits all lanes
      a = (__logf(S) + m) + bcur;        // np-ordered final adds
      ao[(size_t)t * 32 + j] = a;        // halves write same value -> safe
    }
    // evidence = logsumexp(alpha[T-1]) — np-exact, identical to baseline
    float z[32];
#pragma unroll
    for (int i = 0; i < 32; ++i) z[i] = rdlane(a, i);
    float m = max32(z);
#pragma unroll
    for (int i = 0; i < 32; ++i) z[i] = __expf(z[i] - m);
    float S = npsum32(z);
    if (lane == 0) ev[b] = __logf(S) + m;
  } else {
    float arow[16];                      // A[j][i0+k]
#pragma unroll
    for (int k = 0; k < 16; ++k) {
      arow[k] = logA[j * 32 + i0 + k];
      asm volatile("" : "+v"(arow[k]));
    }
    float* bo = bet + (size_t)b * Tt * 32;
    bo[(size_t)(Tt - 1) * 32 + j] = 0.f;
    float y = lb[(size_t)(Tt - 1) * 32 + j] + 0.f;   // (logB[T-1] + beta[T-1])
    float bA = lb[(size_t)(Tt - 2) * 32 + j];
    float bB = lb[(size_t)(Tt - 3) * 32 + j];
    float bC = lb[(size_t)(Tt - 4) * 32 + j];
#pragma unroll 1
    for (int t = Tt - 2; t >= 0; --t) {
      float bcur = bA; bA = bB; bB = bC;
      if (t >= 3) bC = lb[(size_t)(t - 3) * 32 + j];
      float sy[32];                      // uniform (SGPR) gather of y-vector
#pragma unroll
      for (int i = 0; i < 32; ++i) sy[i] = rdlane(y, i);
      float z[16];
      if (h == 0) {
#pragma unroll
        for (int k = 0; k < 16; ++k) z[k] = arow[k] + sy[k];      // A[j][i]+y_i
      } else {
#pragma unroll
        for (int k = 0; k < 16; ++k) z[k] = arow[k] + sy[16 + k];
      }
      float mh = max16(z);
      float mlo, mhi;
      xhalf(mh, mlo, mhi);
      float m = fmaxf(mlo, mhi);
      float e[16];
#pragma unroll
      for (int k = 0; k < 16; ++k) e[k] = __expf(z[k] - m);
      float sh = sum16(e);
      float slo, shi;
      xhalf(sh, slo, shi);
      float S = slo + shi;
      float bv = __logf(S) + m;          // beta[t][j], same bits both halves
      bo[(size_t)t * 32 + j] = bv;
      y = bcur + bv;                     // (logB[t] + beta[t]) for next step
    }
  }
}

// ---------------- K5: gamma = (alpha + beta) - evidence, fp32 ----------------
__global__ void k_gamma(const float* __restrict__ ws, float* __restrict__ out) {
  size_t idx = (size_t)blockIdx.x * blockDim.x + threadIdx.x;
  if (idx >= (size_t)NB * Tt * 32) return;
  int b = (int)(idx >> 17);            // T*S = 131072
  float a  = out[idx];
  float bb = ws[OFF_BET + idx];
  float e  = ws[OFF_EV + b];
  out[idx] = (a + bb) - e;
}

extern "C" void kernel_launch(void* const* d_in, const int* in_sizes, int n_in,
                              void* d_out, int out_size, void* d_ws, size_t ws_size,
                              hipStream_t stream) {
  const float* x     = (const float*)d_in[0];
  const float* means = (const float*)d_in[1];
  const float* covs  = (const float*)d_in[2];
  const float* logA  = (const float*)d_in[3];
  const float* logpi = (const float*)d_in[4];
  float* ws  = (float*)d_ws;
  float* out = (float*)d_out;

  k_chol<<<dim3(32), dim3(64), 0, stream>>>(covs, means, ws);
  k_emis<<<dim3(4096), dim3(64), 0, stream>>>(x, ws, ws + OFF_LB);
  k_fb<<<dim3(32), dim3(64), 0, stream>>>(logA, logpi, ws, out);
  k_gamma<<<dim3(8192), dim3(256), 0, stream>>>(ws, out);
}